// Round 3
// baseline (126.583 us; speedup 1.0000x reference)
//
#include <hip/hip_runtime.h>

// RBF kernel: out[i][j] = exp(-||x_i - y_j||^2), x,y: [8192][512] fp32.
// ||x-y||^2 = x2[i] + y2[j] - 2*dot(x_i,y_j); cross term = bf16 MFMA GEMM.
// R2: 128x128 tile / 256 threads / 64 KiB LDS -> 2 blocks/CU, so one block's
// epilogue (HBM writes, the 40us floor) overlaps the other's MFMA K-loop.
// Schedule is R1's verbatim: 4 phases/K-tile, counted vmcnt, XOR swizzle,
// setprio around MFMA; plus bijective XCD blockIdx swizzle.

typedef short bf16x8 __attribute__((ext_vector_type(8)));
typedef float f32x4 __attribute__((ext_vector_type(4)));

#define NROWS 8192
#define DIM 512
#define NK 8   // K-tiles of BK=64
#define BM 128
#define BN 128

__device__ __forceinline__ unsigned short f2bf(float f) {
  unsigned int u = __float_as_uint(f);
  u += 0x7fffu + ((u >> 16) & 1u);
  return (unsigned short)(u >> 16);
}

__device__ __forceinline__ void gload_lds16(const void* g, void* l) {
  __builtin_amdgcn_global_load_lds(
      (const __attribute__((address_space(1))) void*)g,
      (__attribute__((address_space(3))) void*)l, 16, 0, 0);
}

// Swizzled LDS read: tile = [128][64] bf16 (row stride 128B = 8 16B-slots).
// LDS[R][s] holds global slot s^(R&7) -> read global slot g at s = g^(R&7).
// Lanes 0..15 (rows r..r+15, fixed g) land on 8 distinct bank-quads -> 2-way.
__device__ __forceinline__ bf16x8 lds_frag(const unsigned short* tb, int R, int g) {
  return *(const bf16x8*)(tb + R * 64 + ((g ^ (R & 7)) << 3));
}

// ---------------------------------------------------------------------------
// Prep: fp32 -> bf16 copies of x and y, plus fp32 row sum-of-squares.
// ---------------------------------------------------------------------------
__global__ void rbf_prep(const float* __restrict__ x, const float* __restrict__ y,
                         unsigned short* __restrict__ xb, unsigned short* __restrict__ yb,
                         float* __restrict__ xsq, float* __restrict__ ysq) {
  int wave = threadIdx.x >> 6;
  int lane = threadIdx.x & 63;
  int row = blockIdx.x * 4 + wave;  // 0..16383
  const float* src;
  unsigned short* dst;
  float* sq;
  int r;
  if (row < NROWS) { src = x; dst = xb; sq = xsq; r = row; }
  else             { src = y; dst = yb; sq = ysq; r = row - NROWS; }

  const float4* p = (const float4*)(src + (size_t)r * DIM);
  float4 v0 = p[lane];
  float4 v1 = p[lane + 64];
  float s = v0.x * v0.x + v0.y * v0.y + v0.z * v0.z + v0.w * v0.w
          + v1.x * v1.x + v1.y * v1.y + v1.z * v1.z + v1.w * v1.w;

  union { uint2 u; unsigned short h[4]; } a, b;
  a.h[0] = f2bf(v0.x); a.h[1] = f2bf(v0.y); a.h[2] = f2bf(v0.z); a.h[3] = f2bf(v0.w);
  b.h[0] = f2bf(v1.x); b.h[1] = f2bf(v1.y); b.h[2] = f2bf(v1.z); b.h[3] = f2bf(v1.w);
  *(uint2*)(dst + (size_t)r * DIM + lane * 4)       = a.u;
  *(uint2*)(dst + (size_t)r * DIM + 256 + lane * 4) = b.u;

  #pragma unroll
  for (int off = 32; off > 0; off >>= 1) s += __shfl_down(s, off);
  if (lane == 0) sq[r] = s;
}

// ---------------------------------------------------------------------------
// 128x128 GEMM + fused RBF epilogue. 256 threads = 4 waves (2x2), each wave
// owns a 64x64 output tile: acc[4][4]. LDS [dbuf][A/B][128x64] = 64 KiB.
// Per K-tile (4 phases):
//   P0: read a(m0-1)+b(n0-1), stage (kt+1).B h0, MFMA Q(0,0)
//   P1: read a(m2-3)+b(n2-3), stage (kt+1).B h1, MFMA Q(1,1)
//   P2: stage (kt+2).A h0 (buf reads done by end of P1), MFMA Q(0,1)
//   P3: stage (kt+2).A h1, MFMA Q(1,0), counted vmcnt(4), barrier.
// ---------------------------------------------------------------------------
__global__ __launch_bounds__(256, 2) void rbf_gemm(
    const unsigned short* __restrict__ xb, const unsigned short* __restrict__ yb,
    const float* __restrict__ xsq, const float* __restrict__ ysq,
    float* __restrict__ out) {
  __shared__ __align__(16) unsigned short lds[2][2][8192];  // [dbuf][A/B][128*64]

  const int t = threadIdx.x;
  const int lane = t & 63;
  const int w = t >> 6;
  const int wr = w >> 1;  // 0..1
  const int wc = w & 1;   // 0..1
  const int ln = lane & 15;
  const int hi = lane >> 4;

  // bijective XCD swizzle: 4096 blocks, 8 XCDs, 512/XCD (8 full row-panels).
  const int bid = ((int)blockIdx.x & 7) * 512 + ((int)blockIdx.x >> 3);
  const int bx = bid & 63;
  const int by = bid >> 6;
  const size_t arow0 = (size_t)by * BM;
  const size_t brow0 = (size_t)bx * BN;

// Stage one 64-row half (h=0/1) of a [128][64] tile: 512 chunks of 16B,
// 2 gload_lds per thread. LDS dest linear; swizzle applied by permuting the
// GLOBAL source column slot (rule #21).
#define STAGE_HALF(d, ab, h, kt)                                            \
  {                                                                         \
    const unsigned short* gsrc_ = (ab) ? yb : xb;                           \
    const size_t grow0_ = ((ab) ? brow0 : arow0) + (h) * 64;                \
    _Pragma("unroll")                                                       \
    for (int r_ = 0; r_ < 2; ++r_) {                                        \
      const int c_ = r_ * 256 + t;      /* chunk 0..511 */                  \
      const int row_ = c_ >> 3;         /* 0..63 */                         \
      const int g_ = (c_ & 7) ^ (row_ & 7);                                 \
      gload_lds16(gsrc_ + (grow0_ + row_) * DIM + (kt) * 64 + g_ * 8,       \
                  &lds[d][ab][(h) * 4096 + c_ * 8]);                        \
    }                                                                       \
  }

#define MFMA_QUAD(mo, no)                                                   \
  _Pragma("unroll")                                                         \
  for (int m_ = 0; m_ < 2; ++m_)                                            \
    _Pragma("unroll")                                                       \
    for (int n_ = 0; n_ < 2; ++n_)                                          \
      _Pragma("unroll")                                                     \
      for (int k_ = 0; k_ < 2; ++k_)                                        \
        acc[(mo) + m_][(no) + n_] = __builtin_amdgcn_mfma_f32_16x16x32_bf16( \
            af[(mo) + m_][k_], bf[(no) + n_][k_], acc[(mo) + m_][(no) + n_], 0, 0, 0);

  f32x4 acc[4][4] = {};

  // Prologue: kt0 A+B fully, kt1 A. 12 loads/thread; vmcnt(4) -> kt0 landed,
  // kt1.A stays in flight (steady-state invariant at loop entry).
  STAGE_HALF(0, 0, 0, 0);
  STAGE_HALF(0, 0, 1, 0);
  STAGE_HALF(0, 1, 0, 0);
  STAGE_HALF(0, 1, 1, 0);
  STAGE_HALF(1, 0, 0, 1);
  STAGE_HALF(1, 0, 1, 1);
  asm volatile("s_waitcnt vmcnt(4)" ::: "memory");
  __builtin_amdgcn_sched_barrier(0);
  __builtin_amdgcn_s_barrier();

  #pragma unroll
  for (int kt = 0; kt < NK; ++kt) {
    const int d = kt & 1;
    const unsigned short* At = lds[d][0];
    const unsigned short* Bt = lds[d][1];

    bf16x8 af[4][2], bf[4][2];

    // ---- P0: read a(m0-1)+b(n0-1); stage (kt+1).B h0; MFMA Q(0,0)
    #pragma unroll
    for (int m = 0; m < 2; ++m)
      #pragma unroll
      for (int k = 0; k < 2; ++k) {
        af[m][k] = lds_frag(At, wr * 64 + m * 16 + ln, k * 4 + hi);
        bf[m][k] = lds_frag(Bt, wc * 64 + m * 16 + ln, k * 4 + hi);
      }
    if (kt + 1 < NK) STAGE_HALF((kt + 1) & 1, 1, 0, kt + 1);
    __builtin_amdgcn_s_barrier();
    asm volatile("s_waitcnt lgkmcnt(0)" ::: "memory");
    __builtin_amdgcn_sched_barrier(0);
    __builtin_amdgcn_s_setprio(1);
    MFMA_QUAD(0, 0);
    __builtin_amdgcn_s_setprio(0);
    __builtin_amdgcn_s_barrier();

    // ---- P1: read a(m2-3)+b(n2-3); stage (kt+1).B h1; MFMA Q(1,1)
    #pragma unroll
    for (int m = 2; m < 4; ++m)
      #pragma unroll
      for (int k = 0; k < 2; ++k) {
        af[m][k] = lds_frag(At, wr * 64 + m * 16 + ln, k * 4 + hi);
        bf[m][k] = lds_frag(Bt, wc * 64 + m * 16 + ln, k * 4 + hi);
      }
    if (kt + 1 < NK) STAGE_HALF((kt + 1) & 1, 1, 1, kt + 1);
    __builtin_amdgcn_s_barrier();
    asm volatile("s_waitcnt lgkmcnt(0)" ::: "memory");
    __builtin_amdgcn_sched_barrier(0);
    __builtin_amdgcn_s_setprio(1);
    MFMA_QUAD(2, 2);
    __builtin_amdgcn_s_setprio(0);
    __builtin_amdgcn_s_barrier();

    // ---- P2: stage (kt+2).A h0 (all buf-d reads done by end of P1); Q(0,1)
    if (kt + 2 < NK) STAGE_HALF(d, 0, 0, kt + 2);
    __builtin_amdgcn_s_barrier();
    __builtin_amdgcn_s_setprio(1);
    MFMA_QUAD(0, 2);
    __builtin_amdgcn_s_setprio(0);
    __builtin_amdgcn_s_barrier();

    // ---- P3: stage (kt+2).A h1; Q(1,0); counted vmcnt; barrier
    if (kt + 2 < NK) STAGE_HALF(d, 0, 1, kt + 2);
    __builtin_amdgcn_s_barrier();
    __builtin_amdgcn_s_setprio(1);
    MFMA_QUAD(2, 0);
    __builtin_amdgcn_s_setprio(0);
    if (kt + 2 < NK) {
      // outstanding = 12: (kt+1).A (4, staged in kt-1), (kt+1).B (4, this kt),
      // (kt+2).A (4, this kt). Leave 4 -> kt+1 fully landed.
      asm volatile("s_waitcnt vmcnt(4)" ::: "memory");
    } else if (kt + 1 < NK) {
      asm volatile("s_waitcnt vmcnt(0)" ::: "memory");  // drain for last tile
    }
    __builtin_amdgcn_sched_barrier(0);
    __builtin_amdgcn_s_barrier();
  }

  // Epilogue: out = exp(-max(x2 + y2 - 2*dot, 0)). Runs with no barrier, so
  // waves drain independently; co-resident block keeps the MFMA pipe fed.
  const size_t orow0 = arow0 + wr * 64;
  const size_t ocol0 = brow0 + wc * 64;
  const int lr = hi * 4;
  const int lc = ln;

  float ys[4];
  #pragma unroll
  for (int ni = 0; ni < 4; ++ni) ys[ni] = ysq[ocol0 + ni * 16 + lc];

  #pragma unroll
  for (int mi = 0; mi < 4; ++mi) {
    float xs[4];
    #pragma unroll
    for (int j = 0; j < 4; ++j) xs[j] = xsq[orow0 + mi * 16 + lr + j];
    #pragma unroll
    for (int ni = 0; ni < 4; ++ni) {
      #pragma unroll
      for (int j = 0; j < 4; ++j) {
        float v = xs[j] + ys[ni] - 2.0f * acc[mi][ni][j];
        v = fmaxf(v, 0.0f);
        out[(orow0 + mi * 16 + lr + j) * (size_t)NROWS + ocol0 + ni * 16 + lc] =
            __expf(-v);
      }
    }
  }
}

// ---------------------------------------------------------------------------
// Fallback (only if ws too small): direct fp32, one thread per output.
// ---------------------------------------------------------------------------
__global__ void rbf_naive(const float* __restrict__ x, const float* __restrict__ y,
                          float* __restrict__ out) {
  int j = blockIdx.x * 16 + (threadIdx.x & 15);
  int i = blockIdx.y * 16 + (threadIdx.x >> 4);
  const float4* xp = (const float4*)(x + (size_t)i * DIM);
  const float4* yp = (const float4*)(y + (size_t)j * DIM);
  float s = 0.f;
  for (int k = 0; k < DIM / 4; ++k) {
    float4 a = xp[k], b = yp[k];
    float d0 = a.x - b.x, d1 = a.y - b.y, d2 = a.z - b.z, d3 = a.w - b.w;
    s += d0 * d0 + d1 * d1 + d2 * d2 + d3 * d3;
  }
  out[(size_t)i * NROWS + j] = __expf(-fmaxf(s, 0.0f));
}

extern "C" void kernel_launch(void* const* d_in, const int* in_sizes, int n_in,
                              void* d_out, int out_size, void* d_ws, size_t ws_size,
                              hipStream_t stream) {
  const float* x = (const float*)d_in[0];
  const float* y = (const float*)d_in[1];
  float* out = (float*)d_out;

  const size_t need = (size_t)16 * 1024 * 1024 + 64 * 1024;
  if (ws_size >= need) {
    unsigned short* xb = (unsigned short*)d_ws;
    unsigned short* yb = xb + (size_t)NROWS * DIM;
    float* xsq = (float*)((char*)d_ws + (size_t)16 * 1024 * 1024);
    float* ysq = xsq + NROWS;

    rbf_prep<<<(2 * NROWS) / 4, 256, 0, stream>>>(x, y, xb, yb, xsq, ysq);
    rbf_gemm<<<(NROWS / BM) * (NROWS / BN), 256, 0, stream>>>(xb, yb, xsq, ysq, out);
  } else {
    dim3 grid(NROWS / 16, NROWS / 16);
    rbf_naive<<<grid, 256, 0, stream>>>(x, y, out);
  }
}

// Round 4
// 112.426 us; speedup vs baseline: 1.1259x; 1.1259x over previous
//
#include <hip/hip_runtime.h>

// RBF kernel: out[i][j] = exp(-||x_i - y_j||^2), x,y: [8192][512] fp32.
// ||x-y||^2 = x2[i] + y2[j] - 2*dot(x_i,y_j); cross term = bf16 MFMA GEMM.
// R3: revert to R1's 256x256 8-wave 4-phase schedule (R2's 128x128+8ph
// reproduced the m232 null). Changes vs R1:
//   - mfma_f32_32x32x16_bf16 (2382 vs 2075 TF ceiling, half the MFMA instrs,
//     same ds_read count), phases partitioned by (ks-pair, nt) to cap
//     live fragments at 12 (peak ~200 VGPR).
//   - epilogue: 32x32 C layout -> 128B store segments; nontemporal stores.
//   - trimmed tail vmcnt/barrier on the last K-tile.

typedef short bf16x8 __attribute__((ext_vector_type(8)));
typedef float f32x16 __attribute__((ext_vector_type(16)));

#define NROWS 8192
#define DIM 512
#define NK 8  // K-tiles of BK=64

__device__ __forceinline__ unsigned short f2bf(float f) {
  unsigned int u = __float_as_uint(f);
  u += 0x7fffu + ((u >> 16) & 1u);
  return (unsigned short)(u >> 16);
}

__device__ __forceinline__ void gload_lds16(const void* g, void* l) {
  __builtin_amdgcn_global_load_lds(
      (const __attribute__((address_space(1))) void*)g,
      (__attribute__((address_space(3))) void*)l, 16, 0, 0);
}

// Swizzled LDS read: half-tile hb = [128][64] bf16 (row stride 128B).
// LDS[R][s] holds global slot s^(R&7) -> read slot g at s = g^(R&7).
__device__ __forceinline__ bf16x8 lds_frag(const unsigned short* hb, int R, int g) {
  return *(const bf16x8*)(hb + R * 64 + ((g ^ (R & 7)) << 3));
}

// ---------------------------------------------------------------------------
// Prep: fp32 -> bf16 copies of x and y, plus fp32 row sum-of-squares.
// ---------------------------------------------------------------------------
__global__ void rbf_prep(const float* __restrict__ x, const float* __restrict__ y,
                         unsigned short* __restrict__ xb, unsigned short* __restrict__ yb,
                         float* __restrict__ xsq, float* __restrict__ ysq) {
  int wave = threadIdx.x >> 6;
  int lane = threadIdx.x & 63;
  int row = blockIdx.x * 4 + wave;  // 0..16383
  const float* src;
  unsigned short* dst;
  float* sq;
  int r;
  if (row < NROWS) { src = x; dst = xb; sq = xsq; r = row; }
  else             { src = y; dst = yb; sq = ysq; r = row - NROWS; }

  const float4* p = (const float4*)(src + (size_t)r * DIM);
  float4 v0 = p[lane];
  float4 v1 = p[lane + 64];
  float s = v0.x * v0.x + v0.y * v0.y + v0.z * v0.z + v0.w * v0.w
          + v1.x * v1.x + v1.y * v1.y + v1.z * v1.z + v1.w * v1.w;

  union { uint2 u; unsigned short h[4]; } a, b;
  a.h[0] = f2bf(v0.x); a.h[1] = f2bf(v0.y); a.h[2] = f2bf(v0.z); a.h[3] = f2bf(v0.w);
  b.h[0] = f2bf(v1.x); b.h[1] = f2bf(v1.y); b.h[2] = f2bf(v1.z); b.h[3] = f2bf(v1.w);
  *(uint2*)(dst + (size_t)r * DIM + lane * 4)       = a.u;
  *(uint2*)(dst + (size_t)r * DIM + 256 + lane * 4) = b.u;

  #pragma unroll
  for (int off = 32; off > 0; off >>= 1) s += __shfl_down(s, off);
  if (lane == 0) sq[r] = s;
}

// ---------------------------------------------------------------------------
// 256x256 GEMM + fused RBF epilogue. 512 threads = 8 waves (2Mx4N), each wave
// owns 128x64 output: acc[mt=4][nt=2] of 32x32 tiles (f32x16 each).
// LDS: [dbuf][A/B][half][128x64] bf16 = 128 KiB, 1 block/CU.
// Per K-tile (4 phases), ks-pair split:
//   P0: read ks01 frags (A 8 + B 4 b128); stage (kt+1).B h0; MFMA nt0/ks01
//   P1: stage (kt+1).B h1; MFMA nt1/ks01
//   P2: read ks23 frags (12); MFMA nt0/ks23   (all buf-d A reads end here)
//   P3: stage (kt+2).A h0+h1; MFMA nt1/ks23; counted vmcnt(4); barrier
// ---------------------------------------------------------------------------
__global__ __launch_bounds__(512, 2) void rbf_gemm(
    const unsigned short* __restrict__ xb, const unsigned short* __restrict__ yb,
    const float* __restrict__ xsq, const float* __restrict__ ysq,
    float* __restrict__ out) {
  __shared__ __align__(16) unsigned short lds[2][2][2][8192];

  const int t = threadIdx.x;
  const int lane = t & 63;
  const int w = t >> 6;
  const int wr = w >> 2;   // 0..1
  const int wc = w & 3;    // 0..3
  const int l31 = lane & 31;
  const int hi2 = lane >> 5;  // 0..1 (k-chunk within K=16)

  const int bx = blockIdx.x & 31;
  const int by = blockIdx.x >> 5;
  const size_t arow0 = (size_t)by * 256;
  const size_t brow0 = (size_t)bx * 256;

  const int sR0 = t >> 3;  // staging row within half (0..63, +64 for r_=1)
  const int ss = t & 7;    // staging 16B slot

// Stage one 128x64 half-tile (2 x global_load_lds per thread). LDS dest is
// linear; swizzle applied by permuting the GLOBAL source column slot.
#define STAGE_HALF(d, ab, h, kt)                                            \
  {                                                                         \
    const unsigned short* gsrc_ = (ab) ? yb : xb;                           \
    const size_t grow0_ = ((ab) ? brow0 : arow0) + (h) * 128;               \
    _Pragma("unroll")                                                       \
    for (int r_ = 0; r_ < 2; ++r_) {                                        \
      const int R_ = sR0 + r_ * 64;                                         \
      const int gcol_ = (kt) * 64 + ((ss ^ (R_ & 7)) << 3);                 \
      gload_lds16(gsrc_ + (grow0_ + R_) * DIM + gcol_,                      \
                  &lds[d][ab][h][r_ * 4096 + w * 512]);                     \
    }                                                                       \
  }

// 8 MFMAs: all 4 mt tiles x one nt x one ks-pair (kk=0,1)
#define MFMA_OCT(afr, bfr, nt)                                              \
  _Pragma("unroll")                                                         \
  for (int m_ = 0; m_ < 4; ++m_)                                            \
    _Pragma("unroll")                                                       \
    for (int k_ = 0; k_ < 2; ++k_)                                          \
      acc[m_][nt] = __builtin_amdgcn_mfma_f32_32x32x16_bf16(                \
          afr[m_][k_], bfr[nt][k_], acc[m_][nt], 0, 0, 0);

  f32x16 acc[4][2] = {};

  // Prologue: kt0 A+B fully, kt1 A. vmcnt(4) -> kt0 landed, kt1.A in flight.
  STAGE_HALF(0, 0, 0, 0);
  STAGE_HALF(0, 0, 1, 0);
  STAGE_HALF(0, 1, 0, 0);
  STAGE_HALF(0, 1, 1, 0);
  STAGE_HALF(1, 0, 0, 1);
  STAGE_HALF(1, 0, 1, 1);
  asm volatile("s_waitcnt vmcnt(4)" ::: "memory");
  __builtin_amdgcn_sched_barrier(0);
  __builtin_amdgcn_s_barrier();

  #pragma unroll
  for (int kt = 0; kt < NK; ++kt) {
    const int d = kt & 1;
    const unsigned short* Ah = lds[d][0][wr];        // wave's 128 A-rows
    const unsigned short* Bh = lds[d][1][wc >> 1];   // wave's B half
    const int Rb = (wc & 1) * 64;                    // wave's 64 B-rows

    // Fragment slot: g = ks*2 + hi2 (8 bf16 = k_local hi2*8..+8 of step ks).
    bf16x8 a01[4][2], a23[4][2], b01[2][2], b23[2][2];

    // ---- P0: read ks-pair0 (A 8, B 4); stage (kt+1).B h0; MFMA nt0/ks01
    #pragma unroll
    for (int m = 0; m < 4; ++m)
      #pragma unroll
      for (int k = 0; k < 2; ++k)
        a01[m][k] = lds_frag(Ah, m * 32 + l31, k * 2 + hi2);
    #pragma unroll
    for (int n = 0; n < 2; ++n)
      #pragma unroll
      for (int k = 0; k < 2; ++k)
        b01[n][k] = lds_frag(Bh, Rb + n * 32 + l31, k * 2 + hi2);
    if (kt + 1 < NK) STAGE_HALF((kt + 1) & 1, 1, 0, kt + 1);
    __builtin_amdgcn_s_barrier();
    asm volatile("s_waitcnt lgkmcnt(0)" ::: "memory");
    __builtin_amdgcn_sched_barrier(0);
    __builtin_amdgcn_s_setprio(1);
    MFMA_OCT(a01, b01, 0);
    __builtin_amdgcn_s_setprio(0);
    __builtin_amdgcn_s_barrier();

    // ---- P1: stage (kt+1).B h1; MFMA nt1/ks01 (frags already in regs)
    if (kt + 1 < NK) STAGE_HALF((kt + 1) & 1, 1, 1, kt + 1);
    __builtin_amdgcn_s_barrier();
    __builtin_amdgcn_s_setprio(1);
    MFMA_OCT(a01, b01, 1);
    __builtin_amdgcn_s_setprio(0);
    __builtin_amdgcn_s_barrier();

    // ---- P2: read ks-pair1 (12 b128); MFMA nt0/ks23
    #pragma unroll
    for (int m = 0; m < 4; ++m)
      #pragma unroll
      for (int k = 0; k < 2; ++k)
        a23[m][k] = lds_frag(Ah, m * 32 + l31, 4 + k * 2 + hi2);
    #pragma unroll
    for (int n = 0; n < 2; ++n)
      #pragma unroll
      for (int k = 0; k < 2; ++k)
        b23[n][k] = lds_frag(Bh, Rb + n * 32 + l31, 4 + k * 2 + hi2);
    __builtin_amdgcn_s_barrier();
    asm volatile("s_waitcnt lgkmcnt(0)" ::: "memory");
    __builtin_amdgcn_sched_barrier(0);
    __builtin_amdgcn_s_setprio(1);
    MFMA_OCT(a23, b23, 0);
    __builtin_amdgcn_s_setprio(0);
    __builtin_amdgcn_s_barrier();

    // ---- P3: stage (kt+2).A h0+h1 (all buf-d A reads done at P2);
    //          MFMA nt1/ks23; counted vmcnt; barrier
    if (kt + 2 < NK) {
      STAGE_HALF(d, 0, 0, kt + 2);
      STAGE_HALF(d, 0, 1, kt + 2);
    }
    __builtin_amdgcn_s_barrier();
    __builtin_amdgcn_s_setprio(1);
    MFMA_OCT(a23, b23, 1);
    __builtin_amdgcn_s_setprio(0);
    if (kt + 2 < NK) {
      // outstanding = 12: (kt+1).A (4), (kt+1).B (4), (kt+2).A (4).
      // Leave 4 -> kt+1 fully landed, kt+2.A in flight.
      asm volatile("s_waitcnt vmcnt(4)" ::: "memory");
    } else if (kt + 1 < NK) {
      asm volatile("s_waitcnt vmcnt(0)" ::: "memory");  // drain for last tile
    }
    __builtin_amdgcn_sched_barrier(0);
    if (kt + 1 < NK) __builtin_amdgcn_s_barrier();
  }

  // Epilogue: out = exp(-max(x2 + y2 - 2*dot, 0)).
  // 32x32 C/D layout: col = lane&31, row = (reg&3) + 8*(reg>>2) + 4*(lane>>5)
  // -> 32-lane 128B contiguous store segments. Nontemporal (never re-read).
  const size_t orow0 = arow0 + wr * 128;
  const size_t ocol0 = brow0 + wc * 64;

  float ysv[2];
  #pragma unroll
  for (int n = 0; n < 2; ++n) ysv[n] = ysq[ocol0 + n * 32 + l31];

  #pragma unroll
  for (int mt = 0; mt < 4; ++mt) {
    #pragma unroll
    for (int j = 0; j < 16; ++j) {
      const int rl = (j & 3) + 8 * (j >> 2) + 4 * hi2;
      const size_t row = orow0 + mt * 32 + rl;
      const float xsv = xsq[row];
      #pragma unroll
      for (int n = 0; n < 2; ++n) {
        float v = xsv + ysv[n] - 2.0f * acc[mt][n][j];
        v = fmaxf(v, 0.0f);
        __builtin_nontemporal_store(
            __expf(-v), &out[row * (size_t)NROWS + ocol0 + n * 32 + l31]);
      }
    }
  }
}

// ---------------------------------------------------------------------------
// Fallback (only if ws too small): direct fp32, one thread per output.
// ---------------------------------------------------------------------------
__global__ void rbf_naive(const float* __restrict__ x, const float* __restrict__ y,
                          float* __restrict__ out) {
  int j = blockIdx.x * 16 + (threadIdx.x & 15);
  int i = blockIdx.y * 16 + (threadIdx.x >> 4);
  const float4* xp = (const float4*)(x + (size_t)i * DIM);
  const float4* yp = (const float4*)(y + (size_t)j * DIM);
  float s = 0.f;
  for (int k = 0; k < DIM / 4; ++k) {
    float4 a = xp[k], b = yp[k];
    float d0 = a.x - b.x, d1 = a.y - b.y, d2 = a.z - b.z, d3 = a.w - b.w;
    s += d0 * d0 + d1 * d1 + d2 * d2 + d3 * d3;
  }
  out[(size_t)i * NROWS + j] = __expf(-fmaxf(s, 0.0f));
}

extern "C" void kernel_launch(void* const* d_in, const int* in_sizes, int n_in,
                              void* d_out, int out_size, void* d_ws, size_t ws_size,
                              hipStream_t stream) {
  const float* x = (const float*)d_in[0];
  const float* y = (const float*)d_in[1];
  float* out = (float*)d_out;

  const size_t need = (size_t)16 * 1024 * 1024 + 64 * 1024;
  if (ws_size >= need) {
    unsigned short* xb = (unsigned short*)d_ws;
    unsigned short* yb = xb + (size_t)NROWS * DIM;
    float* xsq = (float*)((char*)d_ws + (size_t)16 * 1024 * 1024);
    float* ysq = xsq + NROWS;

    rbf_prep<<<(2 * NROWS) / 4, 256, 0, stream>>>(x, y, xb, yb, xsq, ysq);
    rbf_gemm<<<(NROWS / 256) * (NROWS / 256), 512, 0, stream>>>(xb, yb, xsq, ysq, out);
  } else {
    dim3 grid(NROWS / 16, NROWS / 16);
    rbf_naive<<<grid, 256, 0, stream>>>(x, y, out);
  }
}